// Round 2
// baseline (1694.686 us; speedup 1.0000x reference)
//
#include <hip/hip_runtime.h>
#include <hip/hip_bf16.h>

#define EPB 128  // edges per block (= threads per block, 2 waves)

__device__ __forceinline__ unsigned short f2bf(float f) {
    // round-to-nearest-even f32 -> bf16
    unsigned int u = __float_as_uint(f);
    unsigned int r = (u + 0x7fffu + ((u >> 16) & 1u)) >> 16;
    return (unsigned short)r;
}
__device__ __forceinline__ float bfhi(unsigned int u) { return __uint_as_float(u & 0xffff0000u); }
__device__ __forceinline__ float bflo(unsigned int u) { return __uint_as_float(u << 16); }

__global__ void init_out_kernel(const float* __restrict__ x, float* __restrict__ out, int n) {
    int i = blockIdx.x * blockDim.x + threadIdx.x;
    if (i < n) out[i] = x[i];
}

__global__ __launch_bounds__(EPB) void edge_kernel(
    const float* __restrict__ x, const float* __restrict__ cond,
    const float* __restrict__ edge_dist,
    const float* __restrict__ ew1, const float* __restrict__ eb1,
    const float* __restrict__ ew2, const float* __restrict__ eb2,
    const float* __restrict__ cw1, const float* __restrict__ cb1,
    const float* __restrict__ cw2,
    const int* __restrict__ edge_index, const int* __restrict__ tptr,
    float* __restrict__ out, int E)
{
    // per-edge m_input row, bf16. stride 168 (336B = 21*16B): 16B-aligned rows,
    // 84-dword row stride -> bank-start cycles through 8 offsets -> even spread.
    __shared__ __align__(16) unsigned short m_lds[EPB][168];

    const float tval = (float)tptr[0];
    const int tid  = threadIdx.x;
    const int lane = tid & 63;
    const int wid  = tid >> 6;           // 0..1
    const int e0   = blockIdx.x * EPB;

    // ---- gather phase: wave-cooperative, coalesced 252B row reads ----
    #pragma unroll 4
    for (int r = wid; r < EPB; r += (EPB / 64)) {
        int e = e0 + r; if (e >= E) e = E - 1;
        int src = edge_index[e];
        int dst = edge_index[E + e];
        float v0 = (lane < 63) ? cond[src * 63 + lane] : tval;
        float v1 = (lane < 63) ? cond[dst * 63 + lane] : tval;
        m_lds[r][lane]      = f2bf(v0);
        m_lds[r][64 + lane] = f2bf(v1);
    }

    const int e  = e0 + tid;
    const int ee = (e < E) ? e : (E - 1);

    // ---- edge_attr per thread: silu(d*ew1+eb1) @ ew2 + eb2 ----
    {
        float dist = edge_dist[ee];
        float s[32];
        #pragma unroll
        for (int i = 0; i < 32; ++i) {
            float v = fmaf(dist, ew1[i], eb1[i]);
            s[i] = v / (1.f + __expf(-v));
        }
        float ea[32];
        #pragma unroll
        for (int j = 0; j < 32; ++j) ea[j] = eb2[j];
        #pragma unroll
        for (int i = 0; i < 32; ++i) {
            const float* wr = &ew2[i * 32];   // contiguous 128B, uniform -> s_load
            #pragma unroll
            for (int j = 0; j < 32; ++j) ea[j] = fmaf(s[i], wr[j], ea[j]);
        }
        #pragma unroll
        for (int j = 0; j < 32; ++j) m_lds[tid][128 + j] = f2bf(ea[j]);
    }
    __syncthreads();

    // ---- coord MLP: coord_w = silu(m @ cw1 + cb1) @ cw2 ----
    float coord_w = 0.f;
    const unsigned short* mrow = m_lds[tid];
    for (int j0 = 0; j0 < 128; j0 += 16) {
        float acc[16];
        #pragma unroll
        for (int jj = 0; jj < 16; ++jj) acc[jj] = cb1[j0 + jj];
        for (int k0 = 0; k0 < 160; k0 += 8) {
            uint4 u = *reinterpret_cast<const uint4*>(&mrow[k0]);  // ds_read_b128: 8 bf16
            float mk[8];
            mk[0] = bflo(u.x); mk[1] = bfhi(u.x);
            mk[2] = bflo(u.y); mk[3] = bfhi(u.y);
            mk[4] = bflo(u.z); mk[5] = bfhi(u.z);
            mk[6] = bflo(u.w); mk[7] = bfhi(u.w);
            #pragma unroll
            for (int kk = 0; kk < 8; ++kk) {
                const float* wrow = &cw1[(k0 + kk) * 128 + j0];  // uniform -> s_load_dwordx16
                #pragma unroll
                for (int jj = 0; jj < 16; ++jj)
                    acc[jj] = fmaf(mk[kk], wrow[jj], acc[jj]);
            }
        }
        #pragma unroll
        for (int jj = 0; jj < 16; ++jj) {
            float h = acc[jj];
            float sil = h / (1.f + __expf(-h));
            coord_w = fmaf(sil, cw2[j0 + jj], coord_w);
        }
    }

    // ---- epilogue: coord update + scatter-add ----
    if (e < E) {
        int src = edge_index[e];
        int dst = edge_index[E + e];
        float dx = x[src * 3 + 0] - x[dst * 3 + 0];
        float dy = x[src * 3 + 1] - x[dst * 3 + 1];
        float dz = x[src * 3 + 2] - x[dst * 3 + 2];
        float len = sqrtf(fmaf(dx, dx, fmaf(dy, dy, dz * dz)));
        len = fmaxf(len, 1e-8f);
        float sc = coord_w / len;
        atomicAdd(&out[dst * 3 + 0], sc * dx);
        atomicAdd(&out[dst * 3 + 1], sc * dy);
        atomicAdd(&out[dst * 3 + 2], sc * dz);
    }
}

extern "C" void kernel_launch(void* const* d_in, const int* in_sizes, int n_in,
                              void* d_out, int out_size, void* d_ws, size_t ws_size,
                              hipStream_t stream) {
    const float* x         = (const float*)d_in[0];
    const float* cond      = (const float*)d_in[1];
    const float* edge_dist = (const float*)d_in[2];
    const float* ew1       = (const float*)d_in[3];
    const float* eb1       = (const float*)d_in[4];
    const float* ew2       = (const float*)d_in[5];
    const float* eb2       = (const float*)d_in[6];
    // d_in[7..10] = nw1, nb1, nw2, nb2 -> dead code in the reference (h_out discarded)
    const float* cw1       = (const float*)d_in[11];
    const float* cb1       = (const float*)d_in[12];
    const float* cw2       = (const float*)d_in[13];
    const int*   edge_index= (const int*)d_in[14];
    const int*   tptr      = (const int*)d_in[15];
    float* out = (float*)d_out;

    const int E = in_sizes[2];       // 800000
    const int n_out = out_size;      // B*N*3 = 150000

    init_out_kernel<<<(n_out + 255) / 256, 256, 0, stream>>>(x, out, n_out);

    int blocks = (E + EPB - 1) / EPB;
    edge_kernel<<<blocks, EPB, 0, stream>>>(x, cond, edge_dist,
                                            ew1, eb1, ew2, eb2,
                                            cw1, cb1, cw2,
                                            edge_index, tptr, out, E);
}

// Round 3
// 986.647 us; speedup vs baseline: 1.7176x; 1.7176x over previous
//
#include <hip/hip_runtime.h>
#include <hip/hip_bf16.h>

typedef __attribute__((ext_vector_type(8))) short bf16x8;
typedef __attribute__((ext_vector_type(4))) float f32x4;

__device__ __forceinline__ unsigned short f2bf(float f) {
    unsigned int u = __float_as_uint(f);
    unsigned int r = (u + 0x7fffu + ((u >> 16) & 1u)) >> 16;
    return (unsigned short)r;
}

__global__ void init_out_kernel(const float* __restrict__ x, float* __restrict__ out, int n) {
    int i = blockIdx.x * blockDim.x + threadIdx.x;
    if (i < n) out[i] = x[i];
}

// cw1 [160][128] f32 (k,n) -> bt [128][160] bf16 (n,k)  == B^T, rows contiguous in k
__global__ void prep_bt_kernel(const float* __restrict__ cw1, unsigned short* __restrict__ bt) {
    int idx = blockIdx.x * 256 + threadIdx.x;
    if (idx < 160 * 128) {
        int k = idx / 128, n = idx % 128;
        bt[n * 160 + k] = f2bf(cw1[idx]);
    }
}

__global__ __launch_bounds__(256) void edge_mfma_kernel(
    const float* __restrict__ x, const float* __restrict__ cond,
    const float* __restrict__ edge_dist,
    const float* __restrict__ ew1, const float* __restrict__ eb1,
    const float* __restrict__ ew2, const float* __restrict__ eb2,
    const float* __restrict__ cb1, const float* __restrict__ cw2,
    const unsigned short* __restrict__ bt,
    const int* __restrict__ edge_index, const int* __restrict__ tptr,
    float* __restrict__ out, int E)
{
    // m_input tile: 128 edges x 160 feats, bf16, stride 168 shorts (336B = 21*16B)
    __shared__ __align__(16) unsigned short m_lds[128][168];
    __shared__ float cw_lds[128];

    const float tval = (float)tptr[0];
    const int tid  = threadIdx.x;
    const int lane = tid & 63;
    const int wid  = tid >> 6;           // 0..3
    const int e0   = blockIdx.x * 128;

    // ---- gather: 4 waves, coalesced 252B row reads from cond ----
    for (int r = wid; r < 128; r += 4) {
        int e = e0 + r; if (e >= E) e = E - 1;
        int src = edge_index[e];
        int dst = edge_index[E + e];
        float v0 = (lane < 63) ? cond[src * 63 + lane] : tval;
        float v1 = (lane < 63) ? cond[dst * 63 + lane] : tval;
        m_lds[r][lane]      = f2bf(v0);
        m_lds[r][64 + lane] = f2bf(v1);
    }

    // ---- edge_attr: 2 threads per edge (each 16 of 32 outputs) ----
    {
        int r  = tid >> 1;
        int e  = e0 + r; if (e >= E) e = E - 1;
        int j0 = (tid & 1) * 16;
        float dist = edge_dist[e];
        float s[32];
        #pragma unroll
        for (int i = 0; i < 32; ++i) {
            float v = fmaf(dist, ew1[i], eb1[i]);
            s[i] = v / (1.f + __expf(-v));
        }
        float ea[16];
        #pragma unroll
        for (int j = 0; j < 16; ++j) ea[j] = eb2[j0 + j];
        #pragma unroll
        for (int i = 0; i < 32; ++i) {
            const float* wr = &ew2[i * 32 + j0];   // wave-uniform -> s_load
            #pragma unroll
            for (int j = 0; j < 16; ++j) ea[j] = fmaf(s[i], wr[j], ea[j]);
        }
        #pragma unroll
        for (int j = 0; j < 16; ++j) m_lds[r][128 + j0 + j] = f2bf(ea[j]);
    }
    __syncthreads();

    // ---- GEMM via MFMA: wave wid owns edges [wid*32, wid*32+32), all N=128 ----
    // frag layouts (verified m89/m97): arg0 lane: A[row=lane&15][k=8*(lane>>4)+j];
    // arg1 lane: B^T[col=lane&15][k=8*(lane>>4)+j]; D: col=lane&15, row=(lane>>4)*4+reg.
    const int fr = lane & 15;
    const int kq = lane >> 4;

    f32x4 acc[2][8];
    #pragma unroll
    for (int m = 0; m < 2; ++m)
        #pragma unroll
        for (int n = 0; n < 8; ++n)
            acc[m][n] = (f32x4){0.f, 0.f, 0.f, 0.f};

    #pragma unroll
    for (int k0 = 0; k0 < 160; k0 += 32) {
        bf16x8 a[2];
        #pragma unroll
        for (int m = 0; m < 2; ++m) {
            int row = wid * 32 + m * 16 + fr;
            a[m] = *reinterpret_cast<const bf16x8*>(&m_lds[row][k0 + 8 * kq]);
        }
        #pragma unroll
        for (int n = 0; n < 8; ++n) {
            bf16x8 b = *reinterpret_cast<const bf16x8*>(&bt[(n * 16 + fr) * 160 + k0 + 8 * kq]);
            acc[0][n] = __builtin_amdgcn_mfma_f32_16x16x32_bf16(a[0], b, acc[0][n], 0, 0, 0);
            acc[1][n] = __builtin_amdgcn_mfma_f32_16x16x32_bf16(a[1], b, acc[1][n], 0, 0, 0);
        }
    }

    // ---- fused layer-2: coord_w[row] = sum_j silu(H[row][j]) * cw2[j] ----
    // add cb1 (bias of layer 1) before silu; bias is per-column j = n*16+fr.
    #pragma unroll
    for (int m = 0; m < 2; ++m) {
        float psum[4] = {0.f, 0.f, 0.f, 0.f};
        #pragma unroll
        for (int n = 0; n < 8; ++n) {
            float b1 = cb1[n * 16 + fr];
            float w2 = cw2[n * 16 + fr];
            #pragma unroll
            for (int r = 0; r < 4; ++r) {
                float h = acc[m][n][r] + b1;
                float sil = h / (1.f + __expf(-h));
                psum[r] = fmaf(sil, w2, psum[r]);
            }
        }
        #pragma unroll
        for (int off = 1; off < 16; off <<= 1) {
            #pragma unroll
            for (int r = 0; r < 4; ++r)
                psum[r] += __shfl_xor(psum[r], off, 64);
        }
        if (fr == 0) {
            int row0 = wid * 32 + m * 16 + kq * 4;
            #pragma unroll
            for (int r = 0; r < 4; ++r) cw_lds[row0 + r] = psum[r];
        }
    }
    __syncthreads();

    // ---- epilogue: coord update + scatter-add, one thread per edge ----
    if (tid < 128) {
        int e = e0 + tid;
        if (e < E) {
            float coord_w = cw_lds[tid];
            int src = edge_index[e];
            int dst = edge_index[E + e];
            float dx = x[src * 3 + 0] - x[dst * 3 + 0];
            float dy = x[src * 3 + 1] - x[dst * 3 + 1];
            float dz = x[src * 3 + 2] - x[dst * 3 + 2];
            float len = sqrtf(fmaf(dx, dx, fmaf(dy, dy, dz * dz)));
            len = fmaxf(len, 1e-8f);
            float sc = coord_w / len;
            atomicAdd(&out[dst * 3 + 0], sc * dx);
            atomicAdd(&out[dst * 3 + 1], sc * dy);
            atomicAdd(&out[dst * 3 + 2], sc * dz);
        }
    }
}

extern "C" void kernel_launch(void* const* d_in, const int* in_sizes, int n_in,
                              void* d_out, int out_size, void* d_ws, size_t ws_size,
                              hipStream_t stream) {
    const float* x         = (const float*)d_in[0];
    const float* cond      = (const float*)d_in[1];
    const float* edge_dist = (const float*)d_in[2];
    const float* ew1       = (const float*)d_in[3];
    const float* eb1       = (const float*)d_in[4];
    const float* ew2       = (const float*)d_in[5];
    const float* eb2       = (const float*)d_in[6];
    // d_in[7..10] = nw1, nb1, nw2, nb2: dead code (h_out discarded by reference)
    const float* cw1       = (const float*)d_in[11];
    const float* cb1       = (const float*)d_in[12];
    const float* cw2       = (const float*)d_in[13];
    const int*   edge_index= (const int*)d_in[14];
    const int*   tptr      = (const int*)d_in[15];
    float* out = (float*)d_out;

    const int E = in_sizes[2];       // 800000
    const int n_out = out_size;      // 150000

    unsigned short* bt = (unsigned short*)d_ws;  // 128*160 bf16 = 40 KB

    init_out_kernel<<<(n_out + 255) / 256, 256, 0, stream>>>(x, out, n_out);
    prep_bt_kernel<<<(160 * 128 + 255) / 256, 256, 0, stream>>>(cw1, bt);

    int blocks = (E + 127) / 128;
    edge_mfma_kernel<<<blocks, 256, 0, stream>>>(x, cond, edge_dist,
                                                 ew1, eb1, ew2, eb2,
                                                 cb1, cw2, bt,
                                                 edge_index, tptr, out, E);
}

// Round 4
// 297.380 us; speedup vs baseline: 5.6987x; 3.3178x over previous
//
#include <hip/hip_runtime.h>
#include <hip/hip_bf16.h>

typedef __attribute__((ext_vector_type(8))) short bf16x8;
typedef __attribute__((ext_vector_type(4))) float f32x4;
typedef __attribute__((ext_vector_type(4), aligned(4))) float f32x4u;  // 4B-aligned vec load
typedef __attribute__((ext_vector_type(2), aligned(4))) float f32x2u;

__device__ __forceinline__ unsigned short f2bf(float f) {
    unsigned int u = __float_as_uint(f);
    unsigned int r = (u + 0x7fffu + ((u >> 16) & 1u)) >> 16;
    return (unsigned short)r;
}

__global__ void init_out_kernel(const float* __restrict__ x, float* __restrict__ out, int n) {
    int i = blockIdx.x * blockDim.x + threadIdx.x;
    if (i < n) out[i] = x[i];
}

// cw1 [160][128] f32 (k,n) -> bt [128][160] bf16 (n,k)
__global__ void prep_bt_kernel(const float* __restrict__ cw1, unsigned short* __restrict__ bt) {
    int idx = blockIdx.x * 256 + threadIdx.x;
    if (idx < 160 * 128) {
        int k = idx / 128, n = idx % 128;
        bt[n * 160 + k] = f2bf(cw1[idx]);
    }
}

// 8 contiguous floats (4B-aligned) -> bf16x8
__device__ __forceinline__ bf16x8 load8_bf(const float* p) {
    f32x4u a = *(const f32x4u*)p;
    f32x4u b = *(const f32x4u*)(p + 4);
    bf16x8 r;
    r[0] = f2bf(a[0]); r[1] = f2bf(a[1]); r[2] = f2bf(a[2]); r[3] = f2bf(a[3]);
    r[4] = f2bf(b[0]); r[5] = f2bf(b[1]); r[6] = f2bf(b[2]); r[7] = f2bf(b[3]);
    return r;
}
// 7 contiguous floats + tval in slot 7 (row tail: feats 56..62, then timestep)
__device__ __forceinline__ bf16x8 load7t_bf(const float* p, unsigned short tbf) {
    f32x4u a = *(const f32x4u*)p;
    f32x2u b = *(const f32x2u*)(p + 4);
    float c = p[6];
    bf16x8 r;
    r[0] = f2bf(a[0]); r[1] = f2bf(a[1]); r[2] = f2bf(a[2]); r[3] = f2bf(a[3]);
    r[4] = f2bf(b[0]); r[5] = f2bf(b[1]); r[6] = f2bf(c);  r[7] = (short)tbf;
    return r;
}

__global__ __launch_bounds__(256, 4) void edge_mfma_kernel(
    const float* __restrict__ x, const float* __restrict__ cond,
    const float* __restrict__ edge_dist,
    const float* __restrict__ ew1, const float* __restrict__ eb1,
    const float* __restrict__ ew2, const float* __restrict__ eb2,
    const float* __restrict__ cb1, const float* __restrict__ cw2,
    const unsigned short* __restrict__ bt,
    const int* __restrict__ edge_index, const int* __restrict__ tptr,
    float* __restrict__ out, int E)
{
    __shared__ __align__(16) unsigned short ea_lds[128][40];  // 10 KB (stride 80B)
    __shared__ int srcl[128];
    __shared__ int dstl[128];
    __shared__ float cw_lds[128];

    const float tval = (float)tptr[0];
    const unsigned short tbf = f2bf(tval);
    const int tid  = threadIdx.x;
    const int lane = tid & 63;
    const int wid  = tid >> 6;           // 0..3
    const int e0   = blockIdx.x * 128;

    // ---- phase A: waves 0-1 edge_attr; waves 2-3 load edge indices ----
    if (tid < 128) {
        int e = e0 + tid; if (e >= E) e = E - 1;
        float dist = edge_dist[e];
        float s[32];
        #pragma unroll
        for (int i = 0; i < 32; ++i) {
            float v = fmaf(dist, ew1[i], eb1[i]);
            s[i] = v / (1.f + __expf(-v));
        }
        float ea[32];
        #pragma unroll
        for (int j = 0; j < 32; ++j) ea[j] = eb2[j];
        #pragma unroll
        for (int i = 0; i < 32; ++i) {
            const float* wr = &ew2[i * 32];   // uniform row -> s_load
            #pragma unroll
            for (int j = 0; j < 32; ++j) ea[j] = fmaf(s[i], wr[j], ea[j]);
        }
        #pragma unroll
        for (int j = 0; j < 32; ++j) ea_lds[tid][j] = f2bf(ea[j]);
    } else {
        int r = tid - 128;
        int e = e0 + r; if (e >= E) e = E - 1;
        srcl[r] = edge_index[e];
        dstl[r] = edge_index[E + e];
    }
    __syncthreads();

    // ---- gather A-fragments directly into registers ----
    // A-frag (16x16x32): lane(fr,kq) holds A[row=fr][k = 8*kq + j]
    const int fr = lane & 15;
    const int kq = lane >> 4;

    bf16x8 afrag[5][2];
    #pragma unroll
    for (int m = 0; m < 2; ++m) {
        int row = wid * 32 + m * 16 + fr;
        int src = srcl[row];
        int dst = dstl[row];
        const float* sp = cond + (long)src * 63;
        const float* dp = cond + (long)dst * 63;
        // k 0..31 : src feats
        afrag[0][m] = load8_bf(sp + 8 * kq);
        // k 32..63: src feats 32..62 + t (kq==3 tail)
        afrag[1][m] = (kq < 3) ? load8_bf(sp + 32 + 8 * kq) : load7t_bf(sp + 56, tbf);
        // k 64..95: dst feats
        afrag[2][m] = load8_bf(dp + 8 * kq);
        // k 96..127: dst feats 32..62 + t
        afrag[3][m] = (kq < 3) ? load8_bf(dp + 32 + 8 * kq) : load7t_bf(dp + 56, tbf);
        // k 128..159: edge_attr from LDS
        afrag[4][m] = *reinterpret_cast<const bf16x8*>(&ea_lds[row][8 * kq]);
    }

    // ---- GEMM: wave owns 32 edges x 128 cols, N split in two halves ----
    float psum[2][4] = {{0.f,0.f,0.f,0.f},{0.f,0.f,0.f,0.f}};
    #pragma unroll 1
    for (int nh = 0; nh < 2; ++nh) {
        f32x4 acc[2][4];
        #pragma unroll
        for (int m = 0; m < 2; ++m)
            #pragma unroll
            for (int n = 0; n < 4; ++n)
                acc[m][n] = (f32x4){0.f, 0.f, 0.f, 0.f};

        #pragma unroll
        for (int k0t = 0; k0t < 5; ++k0t) {
            #pragma unroll
            for (int n = 0; n < 4; ++n) {
                int col = (nh * 4 + n) * 16 + fr;
                bf16x8 b = *reinterpret_cast<const bf16x8*>(&bt[col * 160 + k0t * 32 + 8 * kq]);
                acc[0][n] = __builtin_amdgcn_mfma_f32_16x16x32_bf16(afrag[k0t][0], b, acc[0][n], 0, 0, 0);
                acc[1][n] = __builtin_amdgcn_mfma_f32_16x16x32_bf16(afrag[k0t][1], b, acc[1][n], 0, 0, 0);
            }
        }
        // fused layer-2 partial: psum += silu(H + cb1) * cw2
        #pragma unroll
        for (int n = 0; n < 4; ++n) {
            int col = (nh * 4 + n) * 16 + fr;
            float b1 = cb1[col];
            float w2 = cw2[col];
            #pragma unroll
            for (int m = 0; m < 2; ++m)
                #pragma unroll
                for (int r = 0; r < 4; ++r) {
                    float h = acc[m][n][r] + b1;
                    float sil = h / (1.f + __expf(-h));
                    psum[m][r] = fmaf(sil, w2, psum[m][r]);
                }
        }
    }

    // reduce over the 16 columns held across fr lanes; D row = kq*4 + r
    #pragma unroll
    for (int off = 1; off < 16; off <<= 1)
        #pragma unroll
        for (int m = 0; m < 2; ++m)
            #pragma unroll
            for (int r = 0; r < 4; ++r)
                psum[m][r] += __shfl_xor(psum[m][r], off, 64);
    if (fr == 0) {
        #pragma unroll
        for (int m = 0; m < 2; ++m) {
            int row0 = wid * 32 + m * 16 + kq * 4;
            #pragma unroll
            for (int r = 0; r < 4; ++r) cw_lds[row0 + r] = psum[m][r];
        }
    }
    __syncthreads();

    // ---- epilogue: coord update + scatter-add ----
    if (tid < 128) {
        int e = e0 + tid;
        if (e < E) {
            float coord_w = cw_lds[tid];
            int src = srcl[tid];
            int dst = dstl[tid];
            float dx = x[src * 3 + 0] - x[dst * 3 + 0];
            float dy = x[src * 3 + 1] - x[dst * 3 + 1];
            float dz = x[src * 3 + 2] - x[dst * 3 + 2];
            float len = sqrtf(fmaf(dx, dx, fmaf(dy, dy, dz * dz)));
            len = fmaxf(len, 1e-8f);
            float sc = coord_w / len;
            atomicAdd(&out[dst * 3 + 0], sc * dx);
            atomicAdd(&out[dst * 3 + 1], sc * dy);
            atomicAdd(&out[dst * 3 + 2], sc * dz);
        }
    }
}

extern "C" void kernel_launch(void* const* d_in, const int* in_sizes, int n_in,
                              void* d_out, int out_size, void* d_ws, size_t ws_size,
                              hipStream_t stream) {
    const float* x         = (const float*)d_in[0];
    const float* cond      = (const float*)d_in[1];
    const float* edge_dist = (const float*)d_in[2];
    const float* ew1       = (const float*)d_in[3];
    const float* eb1       = (const float*)d_in[4];
    const float* ew2       = (const float*)d_in[5];
    const float* eb2       = (const float*)d_in[6];
    // d_in[7..10] = node_mlp weights: dead code (h_out discarded by reference)
    const float* cw1       = (const float*)d_in[11];
    const float* cb1       = (const float*)d_in[12];
    const float* cw2       = (const float*)d_in[13];
    const int*   edge_index= (const int*)d_in[14];
    const int*   tptr      = (const int*)d_in[15];
    float* out = (float*)d_out;

    const int E = in_sizes[2];       // 800000
    const int n_out = out_size;      // 150000

    unsigned short* bt = (unsigned short*)d_ws;  // 128*160 bf16 = 40 KB

    init_out_kernel<<<(n_out + 255) / 256, 256, 0, stream>>>(x, out, n_out);
    prep_bt_kernel<<<(160 * 128 + 255) / 256, 256, 0, stream>>>(cw1, bt);

    int blocks = (E + 127) / 128;
    edge_mfma_kernel<<<blocks, 256, 0, stream>>>(x, cond, edge_dist,
                                                 ew1, eb1, ew2, eb2,
                                                 cb1, cw2, bt,
                                                 edge_index, tptr, out, E);
}

// Round 5
// 271.038 us; speedup vs baseline: 6.2526x; 1.0972x over previous
//
#include <hip/hip_runtime.h>
#include <hip/hip_bf16.h>

typedef __attribute__((ext_vector_type(8))) short bf16x8;
typedef __attribute__((ext_vector_type(4))) float f32x4;
typedef __attribute__((ext_vector_type(4), aligned(4))) float f32x4u;
typedef __attribute__((ext_vector_type(2), aligned(4))) float f32x2u;

__device__ __forceinline__ unsigned short f2bf(float f) {
    unsigned int u = __float_as_uint(f);
    unsigned int r = (u + 0x7fffu + ((u >> 16) & 1u)) >> 16;
    return (unsigned short)r;
}
__device__ __forceinline__ float bf2f(unsigned short u) {
    return __uint_as_float(((unsigned int)u) << 16);
}

__global__ void init_out_kernel(const float* __restrict__ x, float* __restrict__ out, int n) {
    int i = blockIdx.x * blockDim.x + threadIdx.x;
    if (i < n) out[i] = x[i];
}

// bt2[n][k]: W2^T bf16, n in [0,256), k in [0,64). W2[k][n<128] = cw1[k][n] (k<63),
// W2[k][n>=128] = cw1[64+k][n-128] (k<63); k==63 row = 0 (t folded into c0).
__global__ void prep_bt2_kernel(const float* __restrict__ cw1, unsigned short* __restrict__ bt2) {
    int idx = blockIdx.x * 256 + threadIdx.x;
    if (idx < 256 * 64) {
        int n = idx >> 6, k = idx & 63;
        float v = 0.f;
        if (k < 63) v = (n < 128) ? cw1[k * 128 + n] : cw1[(64 + k) * 128 + (n - 128)];
        bt2[n * 64 + k] = f2bf(v);
    }
}

// bt_M[col][p] = (ew2 @ cw1[128:160])^T bf16 [128][32];
// c0[j] = cb1[j] + eb2@cw1[128:160] + t*(cw1[63]+cw1[127])
__global__ void prep_consts_kernel(const float* __restrict__ ew2, const float* __restrict__ eb2,
                                   const float* __restrict__ cw1, const float* __restrict__ cb1,
                                   const int* __restrict__ tptr,
                                   unsigned short* __restrict__ bt_M, float* __restrict__ c0) {
    int j = threadIdx.x;  // 0..127, one block
    float t = (float)tptr[0];
    float cacc = cb1[j] + t * (cw1[63 * 128 + j] + cw1[127 * 128 + j]);
    float m[32];
    #pragma unroll
    for (int p = 0; p < 32; ++p) m[p] = 0.f;
    for (int i = 0; i < 32; ++i) {
        float w = cw1[(128 + i) * 128 + j];
        cacc = fmaf(eb2[i], w, cacc);
        #pragma unroll
        for (int p = 0; p < 32; ++p) m[p] = fmaf(ew2[p * 32 + i], w, m[p]);
    }
    c0[j] = cacc;
    #pragma unroll
    for (int p = 0; p < 32; ++p) bt_M[j * 32 + p] = f2bf(m[p]);
}

__device__ __forceinline__ bf16x8 load8_bf(const float* p) {
    f32x4u a = *(const f32x4u*)p;
    f32x4u b = *(const f32x4u*)(p + 4);
    bf16x8 r;
    r[0] = f2bf(a[0]); r[1] = f2bf(a[1]); r[2] = f2bf(a[2]); r[3] = f2bf(a[3]);
    r[4] = f2bf(b[0]); r[5] = f2bf(b[1]); r[6] = f2bf(b[2]); r[7] = f2bf(b[3]);
    return r;
}
__device__ __forceinline__ bf16x8 load7z_bf(const float* p) {
    f32x4u a = *(const f32x4u*)p;
    f32x2u b = *(const f32x2u*)(p + 4);
    float c = p[6];
    bf16x8 r;
    r[0] = f2bf(a[0]); r[1] = f2bf(a[1]); r[2] = f2bf(a[2]); r[3] = f2bf(a[3]);
    r[4] = f2bf(b[0]); r[5] = f2bf(b[1]); r[6] = f2bf(c);  r[7] = 0;
    return r;
}

// UV[node][256] bf16: cols 0..127 = U = cond@Wtop, cols 128..255 = V = cond@Wmid
__global__ __launch_bounds__(256) void prep_uv_kernel(
    const float* __restrict__ cond, const unsigned short* __restrict__ bt2,
    unsigned short* __restrict__ UV, int BN)
{
    const int tid = threadIdx.x, lane = tid & 63, wid = tid >> 6;
    const int fr = lane & 15, kq = lane >> 4;
    const int base = blockIdx.x * 128 + wid * 32;

    bf16x8 a[2][2];  // [ktile][m]
    #pragma unroll
    for (int m = 0; m < 2; ++m) {
        int node = base + m * 16 + fr; if (node >= BN) node = BN - 1;
        const float* cp = cond + (long)node * 63;
        a[0][m] = load8_bf(cp + 8 * kq);
        a[1][m] = (kq < 3) ? load8_bf(cp + 32 + 8 * kq) : load7z_bf(cp + 56);
    }
    #pragma unroll 1
    for (int nh = 0; nh < 2; ++nh) {
        f32x4 acc[2][8];
        #pragma unroll
        for (int m = 0; m < 2; ++m)
            #pragma unroll
            for (int n = 0; n < 8; ++n) acc[m][n] = (f32x4){0.f, 0.f, 0.f, 0.f};
        #pragma unroll
        for (int n = 0; n < 8; ++n) {
            int col = (nh * 8 + n) * 16 + fr;
            bf16x8 b0 = *reinterpret_cast<const bf16x8*>(&bt2[col * 64 + 8 * kq]);
            bf16x8 b1 = *reinterpret_cast<const bf16x8*>(&bt2[col * 64 + 32 + 8 * kq]);
            acc[0][n] = __builtin_amdgcn_mfma_f32_16x16x32_bf16(a[0][0], b0, acc[0][n], 0, 0, 0);
            acc[0][n] = __builtin_amdgcn_mfma_f32_16x16x32_bf16(a[1][0], b1, acc[0][n], 0, 0, 0);
            acc[1][n] = __builtin_amdgcn_mfma_f32_16x16x32_bf16(a[0][1], b0, acc[1][n], 0, 0, 0);
            acc[1][n] = __builtin_amdgcn_mfma_f32_16x16x32_bf16(a[1][1], b1, acc[1][n], 0, 0, 0);
        }
        #pragma unroll
        for (int m = 0; m < 2; ++m)
            #pragma unroll
            for (int r = 0; r < 4; ++r) {
                int node = base + m * 16 + kq * 4 + r;
                if (node < BN) {
                    #pragma unroll
                    for (int n = 0; n < 8; ++n)
                        UV[(long)node * 256 + (nh * 8 + n) * 16 + fr] = f2bf(acc[m][n][r]);
                }
            }
    }
}

__global__ __launch_bounds__(256, 4) void edge_kernel(
    const float* __restrict__ x, const float* __restrict__ edge_dist,
    const float* __restrict__ ew1, const float* __restrict__ eb1,
    const unsigned short* __restrict__ bt_M, const float* __restrict__ c0f,
    const float* __restrict__ cw2, const unsigned short* __restrict__ UV,
    const int* __restrict__ edge_index, float* __restrict__ out, int E)
{
    __shared__ __align__(16) unsigned short s_lds[128][40];  // 10 KB
    __shared__ int srcl[128];
    __shared__ int dstl[128];
    __shared__ float cw_lds[128];

    const int tid = threadIdx.x, lane = tid & 63, wid = tid >> 6;
    const int fr = lane & 15, kq = lane >> 4;
    const int e0 = blockIdx.x * 128;

    // phase A: waves 0-1 compute s = silu(dist*ew1+eb1); waves 2-3 load indices
    if (tid < 128) {
        int e = e0 + tid; if (e >= E) e = E - 1;
        float dist = edge_dist[e];
        #pragma unroll
        for (int i = 0; i < 32; ++i) {
            float v = fmaf(dist, ew1[i], eb1[i]);
            float s = v / (1.f + __expf(-v));
            s_lds[tid][i] = f2bf(s);
        }
    } else {
        int r = tid - 128;
        int e = e0 + r; if (e >= E) e = E - 1;
        srcl[r] = edge_index[e];
        dstl[r] = edge_index[E + e];
    }
    __syncthreads();

    // A-frags: row(edge)=fr, k=8kq+j
    bf16x8 a[2];
    #pragma unroll
    for (int m = 0; m < 2; ++m)
        a[m] = *reinterpret_cast<const bf16x8*>(&s_lds[wid * 32 + m * 16 + fr][8 * kq]);

    // UV row offsets for the 8 edges this lane owns in D-layout (row=kq*4+r)
    int offu[2][4], offv[2][4];
    #pragma unroll
    for (int m = 0; m < 2; ++m)
        #pragma unroll
        for (int r = 0; r < 4; ++r) {
            int row = wid * 32 + m * 16 + kq * 4 + r;
            offu[m][r] = srcl[row] * 256;
            offv[m][r] = dstl[row] * 256 + 128;
        }

    float psum[2][4] = {{0.f,0.f,0.f,0.f},{0.f,0.f,0.f,0.f}};
    #pragma unroll 1
    for (int nh = 0; nh < 2; ++nh) {
        f32x4 acc[2][4];
        #pragma unroll
        for (int n = 0; n < 4; ++n) {
            float c = c0f[(nh * 4 + n) * 16 + fr];
            acc[0][n] = (f32x4){c, c, c, c};
            acc[1][n] = (f32x4){c, c, c, c};
        }
        #pragma unroll
        for (int n = 0; n < 4; ++n) {
            int col = (nh * 4 + n) * 16 + fr;
            bf16x8 b = *reinterpret_cast<const bf16x8*>(&bt_M[col * 32 + 8 * kq]);
            acc[0][n] = __builtin_amdgcn_mfma_f32_16x16x32_bf16(a[0], b, acc[0][n], 0, 0, 0);
            acc[1][n] = __builtin_amdgcn_mfma_f32_16x16x32_bf16(a[1], b, acc[1][n], 0, 0, 0);
        }
        #pragma unroll
        for (int n = 0; n < 4; ++n) {
            int col = (nh * 4 + n) * 16 + fr;
            float w2 = cw2[col];
            #pragma unroll
            for (int m = 0; m < 2; ++m)
                #pragma unroll
                for (int r = 0; r < 4; ++r) {
                    float uf = bf2f(UV[offu[m][r] + col]);
                    float vf = bf2f(UV[offv[m][r] + col]);
                    float h = acc[m][n][r] + uf + vf;
                    float sil = h / (1.f + __expf(-h));
                    psum[m][r] = fmaf(sil, w2, psum[m][r]);
                }
        }
    }

    // reduce over the 16 fr lanes (cols ≡ fr mod 16)
    #pragma unroll
    for (int off = 1; off < 16; off <<= 1)
        #pragma unroll
        for (int m = 0; m < 2; ++m)
            #pragma unroll
            for (int r = 0; r < 4; ++r)
                psum[m][r] += __shfl_xor(psum[m][r], off, 64);
    if (fr == 0) {
        #pragma unroll
        for (int m = 0; m < 2; ++m) {
            int row0 = wid * 32 + m * 16 + kq * 4;
            #pragma unroll
            for (int r = 0; r < 4; ++r) cw_lds[row0 + r] = psum[m][r];
        }
    }
    __syncthreads();

    if (tid < 128) {
        int e = e0 + tid;
        if (e < E) {
            float coord_w = cw_lds[tid];
            int src = srcl[tid];
            int dst = dstl[tid];
            float dx = x[src * 3 + 0] - x[dst * 3 + 0];
            float dy = x[src * 3 + 1] - x[dst * 3 + 1];
            float dz = x[src * 3 + 2] - x[dst * 3 + 2];
            float len = sqrtf(fmaf(dx, dx, fmaf(dy, dy, dz * dz)));
            len = fmaxf(len, 1e-8f);
            float sc = coord_w / len;
            atomicAdd(&out[dst * 3 + 0], sc * dx);
            atomicAdd(&out[dst * 3 + 1], sc * dy);
            atomicAdd(&out[dst * 3 + 2], sc * dz);
        }
    }
}

extern "C" void kernel_launch(void* const* d_in, const int* in_sizes, int n_in,
                              void* d_out, int out_size, void* d_ws, size_t ws_size,
                              hipStream_t stream) {
    const float* x         = (const float*)d_in[0];
    const float* cond      = (const float*)d_in[1];
    const float* edge_dist = (const float*)d_in[2];
    const float* ew1       = (const float*)d_in[3];
    const float* eb1       = (const float*)d_in[4];
    const float* ew2       = (const float*)d_in[5];
    const float* eb2       = (const float*)d_in[6];
    // d_in[7..10] = node_mlp weights: dead code (h_out discarded by reference)
    const float* cw1       = (const float*)d_in[11];
    const float* cb1       = (const float*)d_in[12];
    const float* cw2       = (const float*)d_in[13];
    const int*   edge_index= (const int*)d_in[14];
    const int*   tptr      = (const int*)d_in[15];
    float* out = (float*)d_out;

    const int E  = in_sizes[2];        // 800000
    const int BN = in_sizes[1] / 63;   // 50000
    const int n_out = out_size;        // 150000

    // workspace layout
    char* ws = (char*)d_ws;
    unsigned short* bt_M = (unsigned short*)(ws);            // 8 KB
    float*          c0   = (float*)(ws + 8192);              // 512 B
    unsigned short* bt2  = (unsigned short*)(ws + 16384);    // 32 KB
    unsigned short* UV   = (unsigned short*)(ws + 65536);    // BN*256*2 = 25.6 MB

    init_out_kernel<<<(n_out + 255) / 256, 256, 0, stream>>>(x, out, n_out);
    prep_bt2_kernel<<<64, 256, 0, stream>>>(cw1, bt2);
    prep_consts_kernel<<<1, 128, 0, stream>>>(ew2, eb2, cw1, cb1, tptr, bt_M, c0);
    prep_uv_kernel<<<(BN + 127) / 128, 256, 0, stream>>>(cond, bt2, UV, BN);

    int blocks = (E + 127) / 128;
    edge_kernel<<<blocks, 256, 0, stream>>>(x, edge_dist, ew1, eb1,
                                            bt_M, c0, cw2, UV,
                                            edge_index, out, E);
}